// Round 2
// baseline (624.264 us; speedup 1.0000x reference)
//
#include <hip/hip_runtime.h>
#include <hip/hip_bf16.h>
#include <math.h>

#define NTOK 4096   // B*S
#define DDIM 1024
#define HDIM 4096
#define EEXP 8
#define NPAIR_PAD (2*NTOK + 1024)   // 128-padded per-expert segments

typedef __attribute__((ext_vector_type(8))) short short8;
typedef __attribute__((ext_vector_type(4))) short short4v;
typedef __attribute__((ext_vector_type(4))) float f32x4;

static __device__ __forceinline__ unsigned short f2bf(float f){
  unsigned int u = __float_as_uint(f);
  u += 0x7FFFu + ((u >> 16) & 1u);
  return (unsigned short)(u >> 16);
}

static __device__ __forceinline__ void gload16(const void* g, void* l){
  __builtin_amdgcn_global_load_lds(
      (const __attribute__((address_space(1))) void*)g,
      (__attribute__((address_space(3))) void*)l, 16, 0, 0);
}

// ---------------- w (f32) -> wb (bf16, pre-swizzled: 16B chunk c stored from src chunk c^(n&7)) ----
__global__ __launch_bounds__(256) void convert_w_kernel(const float* __restrict__ w,
    short* __restrict__ wb, int klog2){
  const int cshift = klog2 - 3;
  size_t i = (size_t)blockIdx.x * 256 + threadIdx.x;   // output chunk index
  size_t n = i >> cshift;
  int c = (int)(i & ((1u << cshift) - 1u));
  int csw = (c & ~7) | ((c ^ (int)n) & 7);
  const float* src = w + (n << klog2) + (size_t)csw * 8;
  f32x4 a = ((const f32x4*)src)[0];
  f32x4 b = ((const f32x4*)src)[1];
  short8 o;
#pragma unroll
  for (int j = 0; j < 4; ++j){ o[j] = (short)f2bf(a[j]); o[j+4] = (short)f2bf(b[j]); }
  *(short8*)(wb + (n << klog2) + (size_t)c * 8) = o;
}

// ---------------- gate: logits, top-2, softmax; also emits xb (bf16 x) and bias-init of out ----
__global__ __launch_bounds__(256) void gate_kernel(const float* __restrict__ x,
    const float* __restrict__ gw, const float* __restrict__ gb,
    const float* __restrict__ b2, float* __restrict__ outF,
    short* __restrict__ xb, int2* __restrict__ te, float2* __restrict__ tw,
    int* __restrict__ cnt){
  const int t = blockIdx.x * 4 + (threadIdx.x >> 6);
  const int l = threadIdx.x & 63;
  const f32x4* xr = (const f32x4*)(x + (size_t)t * DDIM);
  f32x4 xv[4];
#pragma unroll
  for (int j = 0; j < 4; ++j) xv[j] = xr[l + 64*j];
  // x -> bf16
#pragma unroll
  for (int j = 0; j < 4; ++j){
    short4v o;
#pragma unroll
    for (int q = 0; q < 4; ++q) o[q] = (short)f2bf(xv[j][q]);
    ((short4v*)(xb + (size_t)t * DDIM))[l + 64*j] = o;
  }
  float acc[EEXP];
#pragma unroll
  for (int e = 0; e < EEXP; ++e) acc[e] = 0.f;
#pragma unroll
  for (int j = 0; j < 4; ++j){
#pragma unroll
    for (int e = 0; e < EEXP; ++e){
      f32x4 gv = ((const f32x4*)(gw + (size_t)e*DDIM))[l + 64*j];
      acc[e] += xv[j][0]*gv[0] + xv[j][1]*gv[1] + xv[j][2]*gv[2] + xv[j][3]*gv[3];
    }
  }
#pragma unroll
  for (int e = 0; e < EEXP; ++e){
#pragma unroll
    for (int off = 32; off > 0; off >>= 1) acc[e] += __shfl_xor(acc[e], off);
  }
  // all lanes hold full sums; compute top-2 redundantly (no divergence)
  float lg[EEXP];
#pragma unroll
  for (int e = 0; e < EEXP; ++e) lg[e] = acc[e] + gb[e];
  int e0 = 0; float v0 = lg[0];
#pragma unroll
  for (int e = 1; e < EEXP; ++e) if (lg[e] > v0){ v0 = lg[e]; e0 = e; }
  int e1 = -1; float v1 = -1e30f;
#pragma unroll
  for (int e = 0; e < EEXP; ++e) if (e != e0 && lg[e] > v1){ v1 = lg[e]; e1 = e; }
  float r  = expf(v1 - v0);
  float w0 = 1.f / (1.f + r);
  float w1 = r  / (1.f + r);
  if (l == 0){
    outF[(size_t)NTOK*DDIM + 2*t    ] = (float)e0;
    outF[(size_t)NTOK*DDIM + 2*t + 1] = (float)e1;
    te[t] = make_int2(e0, e1);
    tw[t] = make_float2(w0, w1);
    atomicAdd(&cnt[e0], 1);
    atomicAdd(&cnt[e1], 1);
  }
  // out[t,:] = w0*b2[e0,:] + w1*b2[e1,:]
  const f32x4* r0 = (const f32x4*)(b2 + (size_t)e0 * DDIM);
  const f32x4* r1 = (const f32x4*)(b2 + (size_t)e1 * DDIM);
  f32x4* orow = (f32x4*)(outF + (size_t)t * DDIM);
#pragma unroll
  for (int j = 0; j < 4; ++j){
    f32x4 a = r0[l + 64*j], b = r1[l + 64*j], o;
#pragma unroll
    for (int q = 0; q < 4; ++q) o[q] = w0 * a[q] + w1 * b[q];
    orow[l + 64*j] = o;
  }
}

__global__ void scan_kernel(const int* __restrict__ cnt, int* __restrict__ offs){
  if (threadIdx.x == 0){
    int s = 0;
    for (int e = 0; e < EEXP; ++e){ offs[e] = s; s += (cnt[e] + 127) & ~127; }  // 128-pad
  }
}

__global__ __launch_bounds__(256) void scatter_kernel(const int2* __restrict__ te,
    const float2* __restrict__ tw, const int* __restrict__ offs,
    int* __restrict__ cur, int* __restrict__ tokp, float* __restrict__ wtp){
  int t = blockIdx.x * blockDim.x + threadIdx.x;
  if (t >= NTOK) return;
  int2 e = te[t]; float2 w = tw[t];
  int p0 = offs[e.x] + atomicAdd(&cur[e.x], 1);
  tokp[p0] = t; wtp[p0] = w.x;
  int p1 = offs[e.y] + atomicAdd(&cur[e.y], 1);
  tokp[p1] = t; wtp[p1] = w.y;
}

// ---------------- grouped GEMM (global_load_lds staged, XOR-swizzled LDS) ----------------
// PHASE 1: h = GELU(gather(xb) @ w1b^T + b1)   M=cnt[e], N=HDIM, K=DDIM   (h written pre-swizzled)
// PHASE 2: out += wt * (h @ w2b^T)             M=cnt[e], N=DDIM, K=HDIM
#define BM 128
#define BN 128
#define BK 64

template<int PHASE, int KDIM, int NDIM>
__global__ __launch_bounds__(256, 2) void moe_gemm(
    const short* __restrict__ Abase, const short* __restrict__ Wb,
    const float* __restrict__ bias,
    const int* __restrict__ cnts, const int* __restrict__ offs,
    const int* __restrict__ tokp, const float* __restrict__ wtp,
    short* __restrict__ Hout, float* __restrict__ Out){
  const int e   = blockIdx.z;
  const int cnt = cnts[e];
  const int m0  = blockIdx.y * BM;
  if (m0 >= cnt) return;
  const int off   = offs[e];
  const int mrows = min(BM, cnt - m0);
  const int n0    = blockIdx.x * BN;

  __shared__ short As[2][BM * BK];
  __shared__ short Bs[2][BM * BK];

  const int tid  = threadIdx.x;
  const int lane = tid & 63;
  const int wid  = tid >> 6;
  const int wr   = wid >> 1;
  const int wc   = wid & 1;

  const int srow = lane >> 3;   // 0..7 row within 1KB chunk
  const int scol = lane & 7;    // 0..7 16B chunk within 128B row

  const short* wE = Wb + (size_t)e * NDIM * KDIM;

  size_t aSrc[4], bSrc[4];
  int ldsOff[4];
#pragma unroll
  for (int s = 0; s < 4; ++s){
    const int r = wid * 32 + s * 8 + srow;   // LDS row this lane stages
    ldsOff[s] = (wid * 32 + s * 8) * BK;     // wave-uniform chunk base (shorts)
    size_t grow; int acol;
    if (PHASE == 1){
      grow = (size_t)tokp[off + m0 + min(r, mrows - 1)];
      acol = (scol ^ (r & 7)) * 8;           // swizzle the global source (xb is linear)
    } else {
      grow = (size_t)(off + m0 + r);         // h rows compact+128-padded
      acol = scol * 8;                       // h already pre-swizzled
    }
    aSrc[s] = grow * KDIM + acol;
    bSrc[s] = (size_t)(n0 + r) * KDIM + scol * 8;   // wb pre-swizzled
  }

  f32x4 acc[4][4];
#pragma unroll
  for (int i = 0; i < 4; ++i)
#pragma unroll
    for (int j = 0; j < 4; ++j) acc[i][j] = (f32x4){0.f, 0.f, 0.f, 0.f};

  auto STAGE = [&](int buf, int t){
    const int k0 = t * BK;
#pragma unroll
    for (int s = 0; s < 4; ++s)
      gload16(Abase + aSrc[s] + k0, &As[buf][ldsOff[s]]);
#pragma unroll
    for (int s = 0; s < 4; ++s)
      gload16(wE + bSrc[s] + k0, &Bs[buf][ldsOff[s]]);
  };
  auto COMPUTE = [&](int buf){
#pragma unroll
    for (int kk = 0; kk < 2; ++kk){
      short8 af[4], bf[4];
      const int bc = kk * 64 + (lane >> 4) * 16;
#pragma unroll
      for (int i = 0; i < 4; ++i){
        const int rA = wr * 64 + i * 16 + (lane & 15);
        af[i] = *(const short8*)&As[buf][rA * BK + ((bc ^ ((rA & 7) << 4)) >> 1)];
        const int rB = wc * 64 + i * 16 + (lane & 15);
        bf[i] = *(const short8*)&Bs[buf][rB * BK + ((bc ^ ((rB & 7) << 4)) >> 1)];
      }
#pragma unroll
      for (int i = 0; i < 4; ++i)
#pragma unroll
        for (int j = 0; j < 4; ++j)
          acc[i][j] = __builtin_amdgcn_mfma_f32_16x16x32_bf16(af[i], bf[j], acc[i][j], 0, 0, 0);
    }
  };

  const int nk = KDIM / BK;
  STAGE(0, 0);
  __syncthreads();
  int cur = 0;
  for (int t = 0; t < nk - 1; ++t){
    STAGE(cur ^ 1, t + 1);   // issue next-tile loads first (latency hides under MFMA)
    COMPUTE(cur);
    __syncthreads();         // drains vmcnt+lgkm; next buffer ready, this one reusable
    cur ^= 1;
  }
  COMPUTE(cur);

  if (PHASE == 1){
#pragma unroll
    for (int j = 0; j < 4; ++j){
      const int n = n0 + wc * 64 + j * 16 + (lane & 15);
      const float bv = bias[(size_t)e * NDIM + n];
#pragma unroll
      for (int i = 0; i < 4; ++i){
#pragma unroll
        for (int q = 0; q < 4; ++q){
          const int lm = wr * 64 + i * 16 + (lane >> 4) * 4 + q;
          if (lm < mrows){
            float v = acc[i][j][q] + bv;
            v = 0.5f * v * (1.0f + erff(v * 0.70710678118654752f));  // exact GELU
            const int nsw = n ^ ((lm & 7) << 3);                      // pre-swizzle h
            Hout[(size_t)(off + m0 + lm) * NDIM + nsw] = (short)f2bf(v);
          }
        }
      }
    }
  } else {
#pragma unroll
    for (int j = 0; j < 4; ++j){
      const int n = n0 + wc * 64 + j * 16 + (lane & 15);
#pragma unroll
      for (int i = 0; i < 4; ++i){
#pragma unroll
        for (int q = 0; q < 4; ++q){
          const int lm = wr * 64 + i * 16 + (lane >> 4) * 4 + q;
          if (lm < mrows){
            const int p = off + m0 + lm;
            atomicAdd(&Out[(size_t)tokp[p] * NDIM + n], wtp[p] * acc[i][j][q]);
          }
        }
      }
    }
  }
}

extern "C" void kernel_launch(void* const* d_in, const int* in_sizes, int n_in,
                              void* d_out, int out_size, void* d_ws, size_t ws_size,
                              hipStream_t stream){
  const float* x  = (const float*)d_in[0];
  const float* gw = (const float*)d_in[1];
  const float* gb = (const float*)d_in[2];
  const float* w1 = (const float*)d_in[3];
  const float* b1 = (const float*)d_in[4];
  const float* w2 = (const float*)d_in[5];
  const float* b2 = (const float*)d_in[6];
  float* outF = (float*)d_out;

  char* p = (char*)d_ws;
  short* xb = (short*)p;  p += (size_t)NTOK * DDIM * 2;          // 8.4 MB
  short* h  = (short*)p;  p += (size_t)NPAIR_PAD * HDIM * 2;     // 75.5 MB (pre-swizzled bf16)
  short* wb = (short*)p;  p += (size_t)EEXP * HDIM * DDIM * 2;   // 67.1 MB (reused: w1b then w2b)
  int*   tokp = (int*)p;  p += (size_t)NPAIR_PAD * 4;
  float* wtp  = (float*)p;p += (size_t)NPAIR_PAD * 4;
  int2*  te   = (int2*)p; p += (size_t)NTOK * 8;
  float2* tw  = (float2*)p; p += (size_t)NTOK * 8;
  int* meta = (int*)p;    // cnt[8] | offs[8] | cur[8]
  int* cnt  = meta;
  int* offs = meta + 8;
  int* cur  = meta + 16;

  hipMemsetAsync(meta, 0, 24 * sizeof(int), stream);
  gate_kernel<<<NTOK / 4, 256, 0, stream>>>(x, gw, gb, b2, outF, xb, te, tw, cnt);
  scan_kernel<<<1, 64, 0, stream>>>(cnt, offs);
  scatter_kernel<<<(NTOK + 255) / 256, 256, 0, stream>>>(te, tw, offs, cur, tokp, wtp);
  convert_w_kernel<<<16384, 256, 0, stream>>>(w1, wb, 10);   // 8*4096 rows, K=1024
  moe_gemm<1, DDIM, HDIM><<<dim3(HDIM / BN, NTOK / BM, EEXP), 256, 0, stream>>>(
      xb, wb, b1, cnt, offs, tokp, wtp, h, nullptr);
  convert_w_kernel<<<16384, 256, 0, stream>>>(w2, wb, 12);   // 8*1024 rows, K=4096
  moe_gemm<2, HDIM, DDIM><<<dim3(DDIM / BN, NTOK / BM, EEXP), 256, 0, stream>>>(
      h, wb, nullptr, cnt, offs, tokp, wtp, nullptr, outF);
}